// Round 4
// baseline (1467.446 us; speedup 1.0000x reference)
//
#include <hip/hip_runtime.h>

#define NN 100000

// ================= degree count (int) =================
__global__ __launch_bounds__(256) void count_kernel(const int* __restrict__ src,
                                                    const int* __restrict__ dst,
                                                    int* degO, int* degI, int E) {
    int e = blockIdx.x * 256 + threadIdx.x;
    if (e < E) {
        atomicAdd(&degO[src[e]], 1);
        atomicAdd(&degI[dst[e]], 1);
    }
}

__global__ __launch_bounds__(256) void norm_kernel(const int* __restrict__ degO,
                                                   const int* __restrict__ degI,
                                                   float* no, float* ni, int N) {
    int i = blockIdx.x * 256 + threadIdx.x;
    if (i < N) {
        no[i] = rsqrtf(fmaxf((float)degO[i], 1.0f));
        ni[i] = rsqrtf(fmaxf((float)degI[i], 1.0f));
    }
}

// ================= exclusive scan of degI -> row_start (3-phase) =================
__global__ __launch_bounds__(256) void scan1_kernel(const int* __restrict__ deg,
                                                    int* exsc, int* partials, int N) {
    __shared__ int sh[256];
    int i = blockIdx.x * 256 + threadIdx.x;
    int v = (i < N) ? deg[i] : 0;
    sh[threadIdx.x] = v;
    __syncthreads();
    for (int off = 1; off < 256; off <<= 1) {
        int t = (threadIdx.x >= off) ? sh[threadIdx.x - off] : 0;
        __syncthreads();
        sh[threadIdx.x] += t;
        __syncthreads();
    }
    if (i < N) exsc[i] = sh[threadIdx.x] - v;
    if (threadIdx.x == 255) partials[blockIdx.x] = sh[255];
}

__global__ __launch_bounds__(512) void scan2_kernel(int* partials, int nb) {
    __shared__ int sh[512];
    int v = (threadIdx.x < nb) ? partials[threadIdx.x] : 0;
    sh[threadIdx.x] = v;
    __syncthreads();
    for (int off = 1; off < 512; off <<= 1) {
        int t = (threadIdx.x >= off) ? sh[threadIdx.x - off] : 0;
        __syncthreads();
        sh[threadIdx.x] += t;
        __syncthreads();
    }
    if (threadIdx.x < nb) partials[threadIdx.x] = sh[threadIdx.x] - v;  // exclusive
}

__global__ __launch_bounds__(256) void scan3_kernel(int* exsc, const int* __restrict__ partials,
                                                    int* cursor, int N) {
    int i = blockIdx.x * 256 + threadIdx.x;
    if (i < N) {
        int r = exsc[i] + partials[blockIdx.x];
        exsc[i] = r;
        cursor[i] = r;
    }
}

// ================= CSR fill: csr_src[slot(dst)] = src =================
__global__ __launch_bounds__(256) void fill_kernel(const int* __restrict__ src,
                                                   const int* __restrict__ dst,
                                                   int* cursor, int* csr_src, int E) {
    int e = blockIdx.x * 256 + threadIdx.x;
    if (e < E) {
        int pos = atomicAdd(&cursor[dst[e]], 1);
        csr_src[pos] = src[e];
    }
}

// ================= gather-aggregate: out[n] = sum_{e in(n)} h[src(e)] (*no[src]) =================
// TPN lanes per node, lane handles one float4 column-group (active if lane < D4).
template <int D4, int TPN, bool SCALE>
__global__ __launch_bounds__(256) void aggregate_kernel(const float4* __restrict__ h,
                                                        const int* __restrict__ row_start,
                                                        const int* __restrict__ deg,
                                                        const int* __restrict__ csr_src,
                                                        const float* __restrict__ no,
                                                        float4* __restrict__ out, int N) {
    int tid = blockIdx.x * 256 + threadIdx.x;
    int node = tid / TPN;
    int lane = tid % TPN;
    if (node >= N) return;
    const bool active = lane < D4;
    float4 acc = make_float4(0.f, 0.f, 0.f, 0.f);
    const int start = row_start[node];
    const int d = deg[node];
    int j = 0;
    for (; j + 1 < d; j += 2) {
        int s0 = csr_src[start + j];
        int s1 = csr_src[start + j + 1];
        if (active) {
            float4 v0 = h[(size_t)s0 * D4 + lane];
            float4 v1 = h[(size_t)s1 * D4 + lane];
            float c0 = SCALE ? no[s0] : 1.0f;
            float c1 = SCALE ? no[s1] : 1.0f;
            acc.x += v0.x * c0 + v1.x * c1;
            acc.y += v0.y * c0 + v1.y * c1;
            acc.z += v0.z * c0 + v1.z * c1;
            acc.w += v0.w * c0 + v1.w * c1;
        }
    }
    if (j < d) {
        int s0 = csr_src[start + j];
        if (active) {
            float4 v0 = h[(size_t)s0 * D4 + lane];
            float c0 = SCALE ? no[s0] : 1.0f;
            acc.x += v0.x * c0;
            acc.y += v0.y * c0;
            acc.z += v0.z * c0;
            acc.w += v0.w * c0;
        }
    }
    if (active) out[(size_t)node * D4 + lane] = acc;
}

// ====== layer-3 fused aggregate (y is N x 64 padded): out[n,c<47] = relu(agg*nin + b3) ======
template <int D4, int TPN>
__global__ __launch_bounds__(256) void aggregate_final_kernel(const float4* __restrict__ y,
                                                              const int* __restrict__ row_start,
                                                              const int* __restrict__ deg,
                                                              const int* __restrict__ csr_src,
                                                              const float* __restrict__ nin,
                                                              const float* __restrict__ b3,
                                                              float* __restrict__ out, int N) {
    int tid = blockIdx.x * 256 + threadIdx.x;
    int node = tid / TPN;
    int lane = tid % TPN;
    if (node >= N) return;
    const bool active = lane < D4;
    float4 acc = make_float4(0.f, 0.f, 0.f, 0.f);
    const int start = row_start[node];
    const int d = deg[node];
    int j = 0;
    for (; j + 1 < d; j += 2) {
        int s0 = csr_src[start + j];
        int s1 = csr_src[start + j + 1];
        if (active) {
            float4 v0 = y[(size_t)s0 * D4 + lane];
            float4 v1 = y[(size_t)s1 * D4 + lane];
            acc.x += v0.x + v1.x;
            acc.y += v0.y + v1.y;
            acc.z += v0.z + v1.z;
            acc.w += v0.w + v1.w;
        }
    }
    if (j < d) {
        int s0 = csr_src[start + j];
        if (active) {
            float4 v0 = y[(size_t)s0 * D4 + lane];
            acc.x += v0.x;
            acc.y += v0.y;
            acc.z += v0.z;
            acc.w += v0.w;
        }
    }
    if (active) {
        float s = nin[node];
        float vals[4] = {acc.x, acc.y, acc.z, acc.w};
        int c0 = lane * 4;
#pragma unroll
        for (int k = 0; k < 4; ++k) {
            int c = c0 + k;
            if (c < 47) out[(size_t)node * 47 + c] = fmaxf(vals[k] * s + b3[c], 0.0f);
        }
    }
}

// ================= GEMM: out = [relu(] A@W *nin + b [) * nout] =================
// NOTE (empirical, round 3): the TJ=4 / NJ4=3 instantiation scratch-thrashed
// (2.5 GB HBM/dispatch, 815 us). Only use TJ=8 power-of-2 accumulator shapes
// (NJ4 in {2,4}); pad output columns instead (wcols < NOUTP pads with zeros).
template <int K, int NOUTP, int TJ, bool EPI>
__global__ __launch_bounds__(256, 4) void gemm_kernel(const float* __restrict__ A,
                                                      const float* __restrict__ W, const int wcols,
                                                      const float* __restrict__ bias,
                                                      const float* __restrict__ nin,
                                                      const float* __restrict__ nout,
                                                      float* __restrict__ out, const int N) {
    constexpr int BK = 64;
    constexpr int ROWS = 256 / TJ;
    constexpr int M2 = 2;
    constexpr int BM = ROWS * M2;
    constexpr int NJ4 = NOUTP / (TJ * 4);

    __shared__ __align__(16) float Wl[BK * NOUTP];

    const int tid = threadIdx.x;
    const int tj = tid % TJ;
    const int r = tid / TJ;
    const int n0 = blockIdx.x * BM + r * M2;
    const int K4 = K / 4;

    float acc[M2][NJ4 * 4];
#pragma unroll
    for (int m = 0; m < M2; ++m)
#pragma unroll
        for (int j = 0; j < NJ4 * 4; ++j) acc[m][j] = 0.0f;

    const float4* A4 = (const float4*)A;
    const bool v0 = (n0 < N);
    const bool v1 = (n0 + 1 < N);

    for (int k0 = 0; k0 < K; k0 += BK) {
        const int L = (K - k0 < BK) ? (K - k0) : BK;
        for (int i = tid; i < L * NOUTP; i += 256) {
            int k = i / NOUTP;
            int c = i - k * NOUTP;
            Wl[i] = (c < wcols) ? W[(size_t)(k0 + k) * wcols + c] : 0.0f;
        }
        __syncthreads();

        const int L4 = L / 4;
        for (int k4 = 0; k4 < L4; ++k4) {
            float4 a0f = v0 ? A4[(size_t)n0 * K4 + k0 / 4 + k4] : make_float4(0, 0, 0, 0);
            float4 a1f = v1 ? A4[(size_t)(n0 + 1) * K4 + k0 / 4 + k4] : make_float4(0, 0, 0, 0);
            float a0[4] = {a0f.x, a0f.y, a0f.z, a0f.w};
            float a1[4] = {a1f.x, a1f.y, a1f.z, a1f.w};
#pragma unroll
            for (int kk = 0; kk < 4; ++kk) {
#pragma unroll
                for (int jj = 0; jj < NJ4; ++jj) {
                    const float4 w = *(const float4*)&Wl[(k4 * 4 + kk) * NOUTP + (jj * TJ + tj) * 4];
                    acc[0][jj * 4 + 0] = fmaf(a0[kk], w.x, acc[0][jj * 4 + 0]);
                    acc[0][jj * 4 + 1] = fmaf(a0[kk], w.y, acc[0][jj * 4 + 1]);
                    acc[0][jj * 4 + 2] = fmaf(a0[kk], w.z, acc[0][jj * 4 + 2]);
                    acc[0][jj * 4 + 3] = fmaf(a0[kk], w.w, acc[0][jj * 4 + 3]);
                    acc[1][jj * 4 + 0] = fmaf(a1[kk], w.x, acc[1][jj * 4 + 0]);
                    acc[1][jj * 4 + 1] = fmaf(a1[kk], w.y, acc[1][jj * 4 + 1]);
                    acc[1][jj * 4 + 2] = fmaf(a1[kk], w.z, acc[1][jj * 4 + 2]);
                    acc[1][jj * 4 + 3] = fmaf(a1[kk], w.w, acc[1][jj * 4 + 3]);
                }
            }
        }
        __syncthreads();
    }

#pragma unroll
    for (int m = 0; m < M2; ++m) {
        const int n = n0 + m;
        if (n < N) {
            const float s_in = EPI ? nin[n] : 1.0f;
            const float s_out = EPI ? nout[n] : 1.0f;
#pragma unroll
            for (int jj = 0; jj < NJ4; ++jj) {
                const int c0 = (jj * TJ + tj) * 4;
                float v0e = acc[m][jj * 4 + 0] * s_in;
                float v1e = acc[m][jj * 4 + 1] * s_in;
                float v2e = acc[m][jj * 4 + 2] * s_in;
                float v3e = acc[m][jj * 4 + 3] * s_in;
                if (EPI) {
                    v0e = fmaxf(v0e + bias[c0 + 0], 0.0f) * s_out;
                    v1e = fmaxf(v1e + bias[c0 + 1], 0.0f) * s_out;
                    v2e = fmaxf(v2e + bias[c0 + 2], 0.0f) * s_out;
                    v3e = fmaxf(v3e + bias[c0 + 3], 0.0f) * s_out;
                }
                float4 o = make_float4(v0e, v1e, v2e, v3e);
                *(float4*)&out[(size_t)n * NOUTP + c0] = o;
            }
        }
    }
}

extern "C" void kernel_launch(void* const* d_in, const int* in_sizes, int n_in,
                              void* d_out, int out_size, void* d_ws, size_t ws_size,
                              hipStream_t stream) {
    const float* x  = (const float*)d_in[0];
    const int*   ei = (const int*)d_in[1];
    const float* W1 = (const float*)d_in[2];
    const float* b1 = (const float*)d_in[3];
    const float* W2 = (const float*)d_in[4];
    const float* b2 = (const float*)d_in[5];
    const float* W3 = (const float*)d_in[6];
    const float* b3 = (const float*)d_in[7];
    float* out = (float*)d_out;

    const int N = NN;
    const int E = in_sizes[1] / 2;
    const int* src = ei;
    const int* dst = ei + E;

    // ---- workspace layout ----
    float* ws = (float*)d_ws;
    float* norm_out = ws;                       // N f
    float* norm_in  = ws + N;                   // N f
    float* bufA = ws + 2 * (size_t)N;           // N x 128 f (agg; aliased as bufY N x 64)
    float* bufB = bufA + (size_t)N * 128;       // N x 128 f (h)
    int* ip = (int*)(bufB + (size_t)N * 128);
    int* degO      = ip;                        // N i
    int* degI      = ip + N;                    // N i
    int* row_start = ip + 2 * (size_t)N;        // N i
    int* cursor    = ip + 3 * (size_t)N;        // N i
    int* csr_src   = ip + 4 * (size_t)N;        // E i
    int* partials  = csr_src + E;               // 512 i
    float* bufY = bufA;                         // N x 64 (layer-3 y, padded cols 47->64)

    const int NB = (N + 255) / 256;             // 391 scan blocks

    // ---- degrees, norms, CSR ----
    hipMemsetAsync(degO, 0, 2 * (size_t)N * sizeof(int), stream);
    count_kernel<<<(E + 255) / 256, 256, 0, stream>>>(src, dst, degO, degI, E);
    norm_kernel<<<NB, 256, 0, stream>>>(degO, degI, norm_out, norm_in, N);
    scan1_kernel<<<NB, 256, 0, stream>>>(degI, row_start, partials, N);
    scan2_kernel<<<1, 512, 0, stream>>>(partials, NB);
    scan3_kernel<<<NB, 256, 0, stream>>>(row_start, partials, cursor, N);
    fill_kernel<<<(E + 255) / 256, 256, 0, stream>>>(src, dst, cursor, csr_src, E);

    // ---- layer 1: agg1 = gather-agg(x * no, 100); h1' = relu(agg1@W1 *nin + b1) * no ----
    aggregate_kernel<25, 32, true><<<(N * 32 + 255) / 256, 256, 0, stream>>>(
        (const float4*)x, row_start, degI, csr_src, norm_out, (float4*)bufA, N);
    gemm_kernel<100, 128, 8, true><<<(N + 63) / 64, 256, 0, stream>>>(
        bufA, W1, 128, b1, norm_in, norm_out, bufB, N);

    // ---- layer 2: agg2 = gather-agg(h1', 128); h2' = relu(agg2@W2 *nin + b2) * no ----
    aggregate_kernel<32, 32, false><<<(N * 32 + 255) / 256, 256, 0, stream>>>(
        (const float4*)bufB, row_start, degI, csr_src, nullptr, (float4*)bufA, N);
    gemm_kernel<128, 128, 8, true><<<(N + 63) / 64, 256, 0, stream>>>(
        bufA, W2, 128, b2, norm_in, norm_out, bufB, N);

    // ---- layer 3 (reordered): y' = h2'@W3 (padded to 64 cols);
    //      out = relu(gather-agg(y')*nin + b3) ----
    gemm_kernel<128, 64, 8, false><<<(N + 63) / 64, 256, 0, stream>>>(
        bufB, W3, 47, nullptr, nullptr, nullptr, bufY, N);
    aggregate_final_kernel<16, 16><<<(N * 16 + 255) / 256, 256, 0, stream>>>(
        (const float4*)bufY, row_start, degI, csr_src, norm_in, b3, out, N);
}

// Round 5
// 462.581 us; speedup vs baseline: 3.1723x; 3.1723x over previous
//
#include <hip/hip_runtime.h>

#define NN 100000

// ================= degree count (int) =================
__global__ __launch_bounds__(256) void count_kernel(const int* __restrict__ src,
                                                    const int* __restrict__ dst,
                                                    int* degO, int* degI, int E) {
    int e = blockIdx.x * 256 + threadIdx.x;
    if (e < E) {
        atomicAdd(&degO[src[e]], 1);
        atomicAdd(&degI[dst[e]], 1);
    }
}

__global__ __launch_bounds__(256) void norm_kernel(const int* __restrict__ degO,
                                                   const int* __restrict__ degI,
                                                   float* no, float* ni, int N) {
    int i = blockIdx.x * 256 + threadIdx.x;
    if (i < N) {
        no[i] = rsqrtf(fmaxf((float)degO[i], 1.0f));
        ni[i] = rsqrtf(fmaxf((float)degI[i], 1.0f));
    }
}

// ================= exclusive scan of degI -> row_start (3-phase) =================
__global__ __launch_bounds__(256) void scan1_kernel(const int* __restrict__ deg,
                                                    int* exsc, int* partials, int N) {
    __shared__ int sh[256];
    int i = blockIdx.x * 256 + threadIdx.x;
    int v = (i < N) ? deg[i] : 0;
    sh[threadIdx.x] = v;
    __syncthreads();
    for (int off = 1; off < 256; off <<= 1) {
        int t = (threadIdx.x >= off) ? sh[threadIdx.x - off] : 0;
        __syncthreads();
        sh[threadIdx.x] += t;
        __syncthreads();
    }
    if (i < N) exsc[i] = sh[threadIdx.x] - v;
    if (threadIdx.x == 255) partials[blockIdx.x] = sh[255];
}

__global__ __launch_bounds__(512) void scan2_kernel(int* partials, int nb) {
    __shared__ int sh[512];
    int v = (threadIdx.x < nb) ? partials[threadIdx.x] : 0;
    sh[threadIdx.x] = v;
    __syncthreads();
    for (int off = 1; off < 512; off <<= 1) {
        int t = (threadIdx.x >= off) ? sh[threadIdx.x - off] : 0;
        __syncthreads();
        sh[threadIdx.x] += t;
        __syncthreads();
    }
    if (threadIdx.x < nb) partials[threadIdx.x] = sh[threadIdx.x] - v;  // exclusive
}

__global__ __launch_bounds__(256) void scan3_kernel(int* exsc, const int* __restrict__ partials,
                                                    int* cursor, int N) {
    int i = blockIdx.x * 256 + threadIdx.x;
    if (i < N) {
        int r = exsc[i] + partials[blockIdx.x];
        exsc[i] = r;
        cursor[i] = r;
    }
}

// ================= CSR fill: csr_src[slot(dst)] = src =================
__global__ __launch_bounds__(256) void fill_kernel(const int* __restrict__ src,
                                                   const int* __restrict__ dst,
                                                   int* cursor, int* csr_src, int E) {
    int e = blockIdx.x * 256 + threadIdx.x;
    if (e < E) {
        int pos = atomicAdd(&cursor[dst[e]], 1);
        csr_src[pos] = src[e];
    }
}

// ================= gather-aggregate: out[n] = sum_{e in(n)} h[src(e)] (*no[src]) =================
template <int D4, int TPN, bool SCALE>
__global__ __launch_bounds__(256) void aggregate_kernel(const float4* __restrict__ h,
                                                        const int* __restrict__ row_start,
                                                        const int* __restrict__ deg,
                                                        const int* __restrict__ csr_src,
                                                        const float* __restrict__ no,
                                                        float4* __restrict__ out, int N) {
    int tid = blockIdx.x * 256 + threadIdx.x;
    int node = tid / TPN;
    int lane = tid % TPN;
    if (node >= N) return;
    const bool active = lane < D4;
    float4 acc = make_float4(0.f, 0.f, 0.f, 0.f);
    const int start = row_start[node];
    const int d = deg[node];
    int j = 0;
    for (; j + 1 < d; j += 2) {
        int s0 = csr_src[start + j];
        int s1 = csr_src[start + j + 1];
        if (active) {
            float4 v0 = h[(size_t)s0 * D4 + lane];
            float4 v1 = h[(size_t)s1 * D4 + lane];
            float c0 = SCALE ? no[s0] : 1.0f;
            float c1 = SCALE ? no[s1] : 1.0f;
            acc.x += v0.x * c0 + v1.x * c1;
            acc.y += v0.y * c0 + v1.y * c1;
            acc.z += v0.z * c0 + v1.z * c1;
            acc.w += v0.w * c0 + v1.w * c1;
        }
    }
    if (j < d) {
        int s0 = csr_src[start + j];
        if (active) {
            float4 v0 = h[(size_t)s0 * D4 + lane];
            float c0 = SCALE ? no[s0] : 1.0f;
            acc.x += v0.x * c0;
            acc.y += v0.y * c0;
            acc.z += v0.z * c0;
            acc.w += v0.w * c0;
        }
    }
    if (active) out[(size_t)node * D4 + lane] = acc;
}

// ====== layer-3 fused aggregate (y is N x 48 dense): out[n,c<47] = relu(agg*nin + b3) ======
template <int D4, int TPN>
__global__ __launch_bounds__(256) void aggregate_final_kernel(const float4* __restrict__ y,
                                                              const int* __restrict__ row_start,
                                                              const int* __restrict__ deg,
                                                              const int* __restrict__ csr_src,
                                                              const float* __restrict__ nin,
                                                              const float* __restrict__ b3,
                                                              float* __restrict__ out, int N) {
    int tid = blockIdx.x * 256 + threadIdx.x;
    int node = tid / TPN;
    int lane = tid % TPN;
    if (node >= N) return;
    const bool active = lane < D4;
    float4 acc = make_float4(0.f, 0.f, 0.f, 0.f);
    const int start = row_start[node];
    const int d = deg[node];
    int j = 0;
    for (; j + 1 < d; j += 2) {
        int s0 = csr_src[start + j];
        int s1 = csr_src[start + j + 1];
        if (active) {
            float4 v0 = y[(size_t)s0 * D4 + lane];
            float4 v1 = y[(size_t)s1 * D4 + lane];
            acc.x += v0.x + v1.x;
            acc.y += v0.y + v1.y;
            acc.z += v0.z + v1.z;
            acc.w += v0.w + v1.w;
        }
    }
    if (j < d) {
        int s0 = csr_src[start + j];
        if (active) {
            float4 v0 = y[(size_t)s0 * D4 + lane];
            acc.x += v0.x;
            acc.y += v0.y;
            acc.z += v0.z;
            acc.w += v0.w;
        }
    }
    if (active) {
        float s = nin[node];
        float vals[4] = {acc.x, acc.y, acc.z, acc.w};
        int c0 = lane * 4;
#pragma unroll
        for (int k = 0; k < 4; ++k) {
            int c = c0 + k;
            if (c < 47) out[(size_t)node * 47 + c] = fmaxf(vals[k] * s + b3[c], 0.0f);
        }
    }
}

// ================= GEMM: out = epi ? relu(A@W *nin + b)*nout : A@W =================
// EMPIRICAL (rounds 1/3/4): every specially-shaped layer-3 instantiation of this
// template scratch-spilled its accumulators (write-heavy GB-scale HBM traffic).
// Therefore: ONLY the <100,128,8> and <128,128,8> instantiations may exist.
// Epilogue behavior and output stride are RUNTIME params so layer 3 reuses the
// byte-identical healthy kernel. Store predicated on c0 < ostride.
template <int K, int NOUTP, int TJ>
__global__ __launch_bounds__(256, 4) void gemm_kernel(const float* __restrict__ A,
                                                      const float* __restrict__ W, const int wcols,
                                                      const float* __restrict__ bias,
                                                      const float* __restrict__ nin,
                                                      const float* __restrict__ nout,
                                                      float* __restrict__ out, const int N,
                                                      const int epi, const int ostride) {
    constexpr int BK = 64;
    constexpr int ROWS = 256 / TJ;
    constexpr int M2 = 2;
    constexpr int BM = ROWS * M2;
    constexpr int NJ4 = NOUTP / (TJ * 4);

    __shared__ __align__(16) float Wl[BK * NOUTP];

    const int tid = threadIdx.x;
    const int tj = tid % TJ;
    const int r = tid / TJ;
    const int n0 = blockIdx.x * BM + r * M2;
    const int K4 = K / 4;

    float acc[M2][NJ4 * 4];
#pragma unroll
    for (int m = 0; m < M2; ++m)
#pragma unroll
        for (int j = 0; j < NJ4 * 4; ++j) acc[m][j] = 0.0f;

    const float4* A4 = (const float4*)A;
    const bool v0 = (n0 < N);
    const bool v1 = (n0 + 1 < N);

    for (int k0 = 0; k0 < K; k0 += BK) {
        const int L = (K - k0 < BK) ? (K - k0) : BK;
        for (int i = tid; i < L * NOUTP; i += 256) {
            int k = i / NOUTP;
            int c = i - k * NOUTP;
            Wl[i] = (c < wcols) ? W[(size_t)(k0 + k) * wcols + c] : 0.0f;
        }
        __syncthreads();

        const int L4 = L / 4;
        for (int k4 = 0; k4 < L4; ++k4) {
            float4 a0f = v0 ? A4[(size_t)n0 * K4 + k0 / 4 + k4] : make_float4(0, 0, 0, 0);
            float4 a1f = v1 ? A4[(size_t)(n0 + 1) * K4 + k0 / 4 + k4] : make_float4(0, 0, 0, 0);
            float a0[4] = {a0f.x, a0f.y, a0f.z, a0f.w};
            float a1[4] = {a1f.x, a1f.y, a1f.z, a1f.w};
#pragma unroll
            for (int kk = 0; kk < 4; ++kk) {
#pragma unroll
                for (int jj = 0; jj < NJ4; ++jj) {
                    const float4 w = *(const float4*)&Wl[(k4 * 4 + kk) * NOUTP + (jj * TJ + tj) * 4];
                    acc[0][jj * 4 + 0] = fmaf(a0[kk], w.x, acc[0][jj * 4 + 0]);
                    acc[0][jj * 4 + 1] = fmaf(a0[kk], w.y, acc[0][jj * 4 + 1]);
                    acc[0][jj * 4 + 2] = fmaf(a0[kk], w.z, acc[0][jj * 4 + 2]);
                    acc[0][jj * 4 + 3] = fmaf(a0[kk], w.w, acc[0][jj * 4 + 3]);
                    acc[1][jj * 4 + 0] = fmaf(a1[kk], w.x, acc[1][jj * 4 + 0]);
                    acc[1][jj * 4 + 1] = fmaf(a1[kk], w.y, acc[1][jj * 4 + 1]);
                    acc[1][jj * 4 + 2] = fmaf(a1[kk], w.z, acc[1][jj * 4 + 2]);
                    acc[1][jj * 4 + 3] = fmaf(a1[kk], w.w, acc[1][jj * 4 + 3]);
                }
            }
        }
        __syncthreads();
    }

#pragma unroll
    for (int m = 0; m < M2; ++m) {
        const int n = n0 + m;
        if (n < N) {
            const float s_in = epi ? nin[n] : 1.0f;
            const float s_out = epi ? nout[n] : 1.0f;
#pragma unroll
            for (int jj = 0; jj < NJ4; ++jj) {
                const int c0 = (jj * TJ + tj) * 4;
                if (c0 < ostride) {
                    float v0e = acc[m][jj * 4 + 0] * s_in;
                    float v1e = acc[m][jj * 4 + 1] * s_in;
                    float v2e = acc[m][jj * 4 + 2] * s_in;
                    float v3e = acc[m][jj * 4 + 3] * s_in;
                    if (epi) {
                        v0e = fmaxf(v0e + bias[c0 + 0], 0.0f) * s_out;
                        v1e = fmaxf(v1e + bias[c0 + 1], 0.0f) * s_out;
                        v2e = fmaxf(v2e + bias[c0 + 2], 0.0f) * s_out;
                        v3e = fmaxf(v3e + bias[c0 + 3], 0.0f) * s_out;
                    }
                    float4 o = make_float4(v0e, v1e, v2e, v3e);
                    *(float4*)&out[(size_t)n * ostride + c0] = o;
                }
            }
        }
    }
}

extern "C" void kernel_launch(void* const* d_in, const int* in_sizes, int n_in,
                              void* d_out, int out_size, void* d_ws, size_t ws_size,
                              hipStream_t stream) {
    const float* x  = (const float*)d_in[0];
    const int*   ei = (const int*)d_in[1];
    const float* W1 = (const float*)d_in[2];
    const float* b1 = (const float*)d_in[3];
    const float* W2 = (const float*)d_in[4];
    const float* b2 = (const float*)d_in[5];
    const float* W3 = (const float*)d_in[6];
    const float* b3 = (const float*)d_in[7];
    float* out = (float*)d_out;

    const int N = NN;
    const int E = in_sizes[1] / 2;
    const int* src = ei;
    const int* dst = ei + E;

    // ---- workspace layout ----
    float* ws = (float*)d_ws;
    float* norm_out = ws;                       // N f
    float* norm_in  = ws + N;                   // N f
    float* bufA = ws + 2 * (size_t)N;           // N x 128 f (agg; aliased as bufY N x 48)
    float* bufB = bufA + (size_t)N * 128;       // N x 128 f (h)
    int* ip = (int*)(bufB + (size_t)N * 128);
    int* degO      = ip;                        // N i
    int* degI      = ip + N;                    // N i
    int* row_start = ip + 2 * (size_t)N;        // N i
    int* cursor    = ip + 3 * (size_t)N;        // N i
    int* csr_src   = ip + 4 * (size_t)N;        // E i
    int* partials  = csr_src + E;               // 512 i
    float* bufY = bufA;                         // N x 48 dense (layer-3 y)

    const int NB = (N + 255) / 256;             // 391 scan blocks

    // ---- degrees, norms, CSR ----
    hipMemsetAsync(degO, 0, 2 * (size_t)N * sizeof(int), stream);
    count_kernel<<<(E + 255) / 256, 256, 0, stream>>>(src, dst, degO, degI, E);
    norm_kernel<<<NB, 256, 0, stream>>>(degO, degI, norm_out, norm_in, N);
    scan1_kernel<<<NB, 256, 0, stream>>>(degI, row_start, partials, N);
    scan2_kernel<<<1, 512, 0, stream>>>(partials, NB);
    scan3_kernel<<<NB, 256, 0, stream>>>(row_start, partials, cursor, N);
    fill_kernel<<<(E + 255) / 256, 256, 0, stream>>>(src, dst, cursor, csr_src, E);

    // ---- layer 1: agg1 = gather-agg(x * no, 100); h1' = relu(agg1@W1 *nin + b1) * no ----
    aggregate_kernel<25, 32, true><<<(N * 32 + 255) / 256, 256, 0, stream>>>(
        (const float4*)x, row_start, degI, csr_src, norm_out, (float4*)bufA, N);
    gemm_kernel<100, 128, 8><<<(N + 63) / 64, 256, 0, stream>>>(
        bufA, W1, 128, b1, norm_in, norm_out, bufB, N, 1, 128);

    // ---- layer 2: agg2 = gather-agg(h1', 128); h2' = relu(agg2@W2 *nin + b2) * no ----
    aggregate_kernel<32, 32, false><<<(N * 32 + 255) / 256, 256, 0, stream>>>(
        (const float4*)bufB, row_start, degI, csr_src, nullptr, (float4*)bufA, N);
    gemm_kernel<128, 128, 8><<<(N + 63) / 64, 256, 0, stream>>>(
        bufA, W2, 128, b2, norm_in, norm_out, bufB, N, 1, 128);

    // ---- layer 3 (reordered): y = h2'@W3 — SAME instantiation as layer 2, W3 cols
    //      zero-padded 47->128, compact output stride 48; then fused final aggregate ----
    gemm_kernel<128, 128, 8><<<(N + 63) / 64, 256, 0, stream>>>(
        bufB, W3, 47, nullptr, nullptr, nullptr, bufY, N, 0, 48);
    aggregate_final_kernel<12, 16><<<(N * 16 + 255) / 256, 256, 0, stream>>>(
        (const float4*)bufY, row_start, degI, csr_src, norm_in, b3, out, N);
}

// Round 6
// 425.276 us; speedup vs baseline: 3.4506x; 1.0877x over previous
//
#include <hip/hip_runtime.h>

#define NN 100000

// ================= degree count (int) =================
__global__ __launch_bounds__(256) void count_kernel(const int* __restrict__ src,
                                                    const int* __restrict__ dst,
                                                    int* degO, int* degI, int E) {
    int e = blockIdx.x * 256 + threadIdx.x;
    if (e < E) {
        atomicAdd(&degO[src[e]], 1);
        atomicAdd(&degI[dst[e]], 1);
    }
}

__global__ __launch_bounds__(256) void norm_kernel(const int* __restrict__ degO,
                                                   const int* __restrict__ degI,
                                                   float* no, float* ni, int N) {
    int i = blockIdx.x * 256 + threadIdx.x;
    if (i < N) {
        no[i] = rsqrtf(fmaxf((float)degO[i], 1.0f));
        ni[i] = rsqrtf(fmaxf((float)degI[i], 1.0f));
    }
}

// ================= exclusive scan of degI -> row_start (3-phase) =================
__global__ __launch_bounds__(256) void scan1_kernel(const int* __restrict__ deg,
                                                    int* exsc, int* partials, int N) {
    __shared__ int sh[256];
    int i = blockIdx.x * 256 + threadIdx.x;
    int v = (i < N) ? deg[i] : 0;
    sh[threadIdx.x] = v;
    __syncthreads();
    for (int off = 1; off < 256; off <<= 1) {
        int t = (threadIdx.x >= off) ? sh[threadIdx.x - off] : 0;
        __syncthreads();
        sh[threadIdx.x] += t;
        __syncthreads();
    }
    if (i < N) exsc[i] = sh[threadIdx.x] - v;
    if (threadIdx.x == 255) partials[blockIdx.x] = sh[255];
}

__global__ __launch_bounds__(512) void scan2_kernel(int* partials, int nb) {
    __shared__ int sh[512];
    int v = (threadIdx.x < nb) ? partials[threadIdx.x] : 0;
    sh[threadIdx.x] = v;
    __syncthreads();
    for (int off = 1; off < 512; off <<= 1) {
        int t = (threadIdx.x >= off) ? sh[threadIdx.x - off] : 0;
        __syncthreads();
        sh[threadIdx.x] += t;
        __syncthreads();
    }
    if (threadIdx.x < nb) partials[threadIdx.x] = sh[threadIdx.x] - v;  // exclusive
}

__global__ __launch_bounds__(256) void scan3_kernel(int* exsc, const int* __restrict__ partials,
                                                    int* cursor, int N) {
    int i = blockIdx.x * 256 + threadIdx.x;
    if (i < N) {
        int r = exsc[i] + partials[blockIdx.x];
        exsc[i] = r;
        cursor[i] = r;
    }
}

// ================= CSR fill: csr_src[slot(dst)] = src =================
__global__ __launch_bounds__(256) void fill_kernel(const int* __restrict__ src,
                                                   const int* __restrict__ dst,
                                                   int* cursor, int* csr_src, int E) {
    int e = blockIdx.x * 256 + threadIdx.x;
    if (e < E) {
        int pos = atomicAdd(&cursor[dst[e]], 1);
        csr_src[pos] = src[e];
    }
}

// ================= gather-aggregate: out[n] = sum_{e in(n)} h[src(e)] (*no[src]) =================
template <int D4, int TPN, bool SCALE>
__global__ __launch_bounds__(256) void aggregate_kernel(const float4* __restrict__ h,
                                                        const int* __restrict__ row_start,
                                                        const int* __restrict__ deg,
                                                        const int* __restrict__ csr_src,
                                                        const float* __restrict__ no,
                                                        float4* __restrict__ out, int N) {
    int tid = blockIdx.x * 256 + threadIdx.x;
    int node = tid / TPN;
    int lane = tid % TPN;
    if (node >= N) return;
    const bool active = lane < D4;
    float4 acc = make_float4(0.f, 0.f, 0.f, 0.f);
    const int start = row_start[node];
    const int d = deg[node];
    int j = 0;
    for (; j + 1 < d; j += 2) {
        int s0 = csr_src[start + j];
        int s1 = csr_src[start + j + 1];
        if (active) {
            float4 v0 = h[(size_t)s0 * D4 + lane];
            float4 v1 = h[(size_t)s1 * D4 + lane];
            float c0 = SCALE ? no[s0] : 1.0f;
            float c1 = SCALE ? no[s1] : 1.0f;
            acc.x += v0.x * c0 + v1.x * c1;
            acc.y += v0.y * c0 + v1.y * c1;
            acc.z += v0.z * c0 + v1.z * c1;
            acc.w += v0.w * c0 + v1.w * c1;
        }
    }
    if (j < d) {
        int s0 = csr_src[start + j];
        if (active) {
            float4 v0 = h[(size_t)s0 * D4 + lane];
            float c0 = SCALE ? no[s0] : 1.0f;
            acc.x += v0.x * c0;
            acc.y += v0.y * c0;
            acc.z += v0.z * c0;
            acc.w += v0.w * c0;
        }
    }
    if (active) out[(size_t)node * D4 + lane] = acc;
}

// ====== layer-3 fused aggregate (y is N x 48 dense): out[n,c<47] = relu(agg*nin + b3) ======
template <int D4, int TPN>
__global__ __launch_bounds__(256) void aggregate_final_kernel(const float4* __restrict__ y,
                                                              const int* __restrict__ row_start,
                                                              const int* __restrict__ deg,
                                                              const int* __restrict__ csr_src,
                                                              const float* __restrict__ nin,
                                                              const float* __restrict__ b3,
                                                              float* __restrict__ out, int N) {
    int tid = blockIdx.x * 256 + threadIdx.x;
    int node = tid / TPN;
    int lane = tid % TPN;
    if (node >= N) return;
    const bool active = lane < D4;
    float4 acc = make_float4(0.f, 0.f, 0.f, 0.f);
    const int start = row_start[node];
    const int d = deg[node];
    int j = 0;
    for (; j + 1 < d; j += 2) {
        int s0 = csr_src[start + j];
        int s1 = csr_src[start + j + 1];
        if (active) {
            float4 v0 = y[(size_t)s0 * D4 + lane];
            float4 v1 = y[(size_t)s1 * D4 + lane];
            acc.x += v0.x + v1.x;
            acc.y += v0.y + v1.y;
            acc.z += v0.z + v1.z;
            acc.w += v0.w + v1.w;
        }
    }
    if (j < d) {
        int s0 = csr_src[start + j];
        if (active) {
            float4 v0 = y[(size_t)s0 * D4 + lane];
            acc.x += v0.x;
            acc.y += v0.y;
            acc.z += v0.z;
            acc.w += v0.w;
        }
    }
    if (active) {
        float s = nin[node];
        float vals[4] = {acc.x, acc.y, acc.z, acc.w};
        int c0 = lane * 4;
#pragma unroll
        for (int k = 0; k < 4; ++k) {
            int c = c0 + k;
            if (c < 47) out[(size_t)node * 47 + c] = fmaxf(vals[k] * s + b3[c], 0.0f);
        }
    }
}

// ================= GEMM: out = epi ? relu(A@W *nin + b)*nout : A@W =================
// EMPIRICAL (rounds 1/3/4): specially-shaped layer-3 instantiations scratch-spilled.
// ONLY <100,128,8> and <128,128,8> may exist; layer 3 reuses <128,128,8> with
// runtime epi=0/ostride=48 (W3 cols zero-padded via wcols=47).
// Round 6: branch-free inner loop (clamped row pointers) + explicit 1-deep
// register prefetch of A across iterations AND chunk barriers.
template <int K, int NOUTP, int TJ>
__global__ __launch_bounds__(256, 4) void gemm_kernel(const float* __restrict__ A,
                                                      const float* __restrict__ W, const int wcols,
                                                      const float* __restrict__ bias,
                                                      const float* __restrict__ nin,
                                                      const float* __restrict__ nout,
                                                      float* __restrict__ out, const int N,
                                                      const int epi, const int ostride) {
    constexpr int BK = 64;
    constexpr int ROWS = 256 / TJ;
    constexpr int M2 = 2;
    constexpr int BM = ROWS * M2;
    constexpr int NJ4 = NOUTP / (TJ * 4);
    constexpr int K4 = K / 4;
    constexpr int NCH = (K + BK - 1) / BK;

    __shared__ __align__(16) float Wl[BK * NOUTP];

    const int tid = threadIdx.x;
    const int tj = tid % TJ;
    const int r = tid / TJ;
    const int n0 = blockIdx.x * BM + r * M2;

    // clamped row pointers: invalid rows read row N-1 (garbage acc, never stored)
    const int ra = (n0 < N) ? n0 : (N - 1);
    const int rb = (n0 + 1 < N) ? (n0 + 1) : (N - 1);
    const float4* __restrict__ pA0 = (const float4*)A + (size_t)ra * K4;
    const float4* __restrict__ pA1 = (const float4*)A + (size_t)rb * K4;

    float acc[M2][NJ4 * 4];
#pragma unroll
    for (int m = 0; m < M2; ++m)
#pragma unroll
        for (int j = 0; j < NJ4 * 4; ++j) acc[m][j] = 0.0f;

    // prefetch first A vectors
    float4 a0n = pA0[0];
    float4 a1n = pA1[0];

    for (int ch = 0; ch < NCH; ++ch) {
        const int k0 = ch * BK;
        const int L = (K - k0 < BK) ? (K - k0) : BK;
        for (int i = tid; i < L * NOUTP; i += 256) {
            int k = i / NOUTP;
            int c = i - k * NOUTP;
            Wl[i] = (c < wcols) ? W[(size_t)(k0 + k) * wcols + c] : 0.0f;
        }
        __syncthreads();

        const int L4 = L / 4;
        for (int k4 = 0; k4 < L4; ++k4) {
            float4 a0f = a0n;
            float4 a1f = a1n;
            const int nk = k0 / 4 + k4 + 1;     // next global k4 (crosses chunk boundary)
            if (nk < K4) {
                a0n = pA0[nk];
                a1n = pA1[nk];
            }
            float a0[4] = {a0f.x, a0f.y, a0f.z, a0f.w};
            float a1[4] = {a1f.x, a1f.y, a1f.z, a1f.w};
#pragma unroll
            for (int kk = 0; kk < 4; ++kk) {
#pragma unroll
                for (int jj = 0; jj < NJ4; ++jj) {
                    const float4 w = *(const float4*)&Wl[(k4 * 4 + kk) * NOUTP + (jj * TJ + tj) * 4];
                    acc[0][jj * 4 + 0] = fmaf(a0[kk], w.x, acc[0][jj * 4 + 0]);
                    acc[0][jj * 4 + 1] = fmaf(a0[kk], w.y, acc[0][jj * 4 + 1]);
                    acc[0][jj * 4 + 2] = fmaf(a0[kk], w.z, acc[0][jj * 4 + 2]);
                    acc[0][jj * 4 + 3] = fmaf(a0[kk], w.w, acc[0][jj * 4 + 3]);
                    acc[1][jj * 4 + 0] = fmaf(a1[kk], w.x, acc[1][jj * 4 + 0]);
                    acc[1][jj * 4 + 1] = fmaf(a1[kk], w.y, acc[1][jj * 4 + 1]);
                    acc[1][jj * 4 + 2] = fmaf(a1[kk], w.z, acc[1][jj * 4 + 2]);
                    acc[1][jj * 4 + 3] = fmaf(a1[kk], w.w, acc[1][jj * 4 + 3]);
                }
            }
        }
        __syncthreads();
    }

#pragma unroll
    for (int m = 0; m < M2; ++m) {
        const int n = n0 + m;
        if (n < N) {
            const float s_in = epi ? nin[n] : 1.0f;
            const float s_out = epi ? nout[n] : 1.0f;
#pragma unroll
            for (int jj = 0; jj < NJ4; ++jj) {
                const int c0 = (jj * TJ + tj) * 4;
                if (c0 < ostride) {
                    float v0e = acc[m][jj * 4 + 0] * s_in;
                    float v1e = acc[m][jj * 4 + 1] * s_in;
                    float v2e = acc[m][jj * 4 + 2] * s_in;
                    float v3e = acc[m][jj * 4 + 3] * s_in;
                    if (epi) {
                        v0e = fmaxf(v0e + bias[c0 + 0], 0.0f) * s_out;
                        v1e = fmaxf(v1e + bias[c0 + 1], 0.0f) * s_out;
                        v2e = fmaxf(v2e + bias[c0 + 2], 0.0f) * s_out;
                        v3e = fmaxf(v3e + bias[c0 + 3], 0.0f) * s_out;
                    }
                    float4 o = make_float4(v0e, v1e, v2e, v3e);
                    *(float4*)&out[(size_t)n * ostride + c0] = o;
                }
            }
        }
    }
}

extern "C" void kernel_launch(void* const* d_in, const int* in_sizes, int n_in,
                              void* d_out, int out_size, void* d_ws, size_t ws_size,
                              hipStream_t stream) {
    const float* x  = (const float*)d_in[0];
    const int*   ei = (const int*)d_in[1];
    const float* W1 = (const float*)d_in[2];
    const float* b1 = (const float*)d_in[3];
    const float* W2 = (const float*)d_in[4];
    const float* b2 = (const float*)d_in[5];
    const float* W3 = (const float*)d_in[6];
    const float* b3 = (const float*)d_in[7];
    float* out = (float*)d_out;

    const int N = NN;
    const int E = in_sizes[1] / 2;
    const int* src = ei;
    const int* dst = ei + E;

    // ---- workspace layout ----
    float* ws = (float*)d_ws;
    float* norm_out = ws;                       // N f
    float* norm_in  = ws + N;                   // N f
    float* bufA = ws + 2 * (size_t)N;           // N x 128 f (agg; aliased as bufY N x 48)
    float* bufB = bufA + (size_t)N * 128;       // N x 128 f (h)
    int* ip = (int*)(bufB + (size_t)N * 128);
    int* degO      = ip;                        // N i
    int* degI      = ip + N;                    // N i
    int* row_start = ip + 2 * (size_t)N;        // N i
    int* cursor    = ip + 3 * (size_t)N;        // N i
    int* csr_src   = ip + 4 * (size_t)N;        // E i
    int* partials  = csr_src + E;               // 512 i
    float* bufY = bufA;                         // N x 48 dense (layer-3 y)

    const int NB = (N + 255) / 256;             // 391 scan blocks

    // ---- degrees, norms, CSR ----
    hipMemsetAsync(degO, 0, 2 * (size_t)N * sizeof(int), stream);
    count_kernel<<<(E + 255) / 256, 256, 0, stream>>>(src, dst, degO, degI, E);
    norm_kernel<<<NB, 256, 0, stream>>>(degO, degI, norm_out, norm_in, N);
    scan1_kernel<<<NB, 256, 0, stream>>>(degI, row_start, partials, N);
    scan2_kernel<<<1, 512, 0, stream>>>(partials, NB);
    scan3_kernel<<<NB, 256, 0, stream>>>(row_start, partials, cursor, N);
    fill_kernel<<<(E + 255) / 256, 256, 0, stream>>>(src, dst, cursor, csr_src, E);

    // ---- layer 1: agg1 = gather-agg(x * no, 100); h1' = relu(agg1@W1 *nin + b1) * no ----
    aggregate_kernel<25, 32, true><<<(N * 32 + 255) / 256, 256, 0, stream>>>(
        (const float4*)x, row_start, degI, csr_src, norm_out, (float4*)bufA, N);
    gemm_kernel<100, 128, 8><<<(N + 63) / 64, 256, 0, stream>>>(
        bufA, W1, 128, b1, norm_in, norm_out, bufB, N, 1, 128);

    // ---- layer 2: agg2 = gather-agg(h1', 128); h2' = relu(agg2@W2 *nin + b2) * no ----
    aggregate_kernel<32, 32, false><<<(N * 32 + 255) / 256, 256, 0, stream>>>(
        (const float4*)bufB, row_start, degI, csr_src, nullptr, (float4*)bufA, N);
    gemm_kernel<128, 128, 8><<<(N + 63) / 64, 256, 0, stream>>>(
        bufA, W2, 128, b2, norm_in, norm_out, bufB, N, 1, 128);

    // ---- layer 3 (reordered): y = h2'@W3 — SAME instantiation as layer 2, W3 cols
    //      zero-padded 47->128, compact output stride 48; then fused final aggregate ----
    gemm_kernel<128, 128, 8><<<(N + 63) / 64, 256, 0, stream>>>(
        bufB, W3, 47, nullptr, nullptr, nullptr, bufY, N, 0, 48);
    aggregate_final_kernel<12, 16><<<(N * 16 + 255) / 256, 256, 0, stream>>>(
        (const float4*)bufY, row_start, degI, csr_src, norm_in, b3, out, N);
}

// Round 7
// 406.623 us; speedup vs baseline: 3.6089x; 1.0459x over previous
//
#include <hip/hip_runtime.h>

#define NN 100000

// ================= degree count (int) =================
__global__ __launch_bounds__(256) void count_kernel(const int* __restrict__ src,
                                                    const int* __restrict__ dst,
                                                    int* degO, int* degI, int E) {
    int e = blockIdx.x * 256 + threadIdx.x;
    if (e < E) {
        atomicAdd(&degO[src[e]], 1);
        atomicAdd(&degI[dst[e]], 1);
    }
}

__global__ __launch_bounds__(256) void norm_kernel(const int* __restrict__ degO,
                                                   const int* __restrict__ degI,
                                                   float* no, float* ni, int N) {
    int i = blockIdx.x * 256 + threadIdx.x;
    if (i < N) {
        no[i] = rsqrtf(fmaxf((float)degO[i], 1.0f));
        ni[i] = rsqrtf(fmaxf((float)degI[i], 1.0f));
    }
}

// ================= exclusive scan of degI -> row_start (3-phase) =================
__global__ __launch_bounds__(256) void scan1_kernel(const int* __restrict__ deg,
                                                    int* exsc, int* partials, int N) {
    __shared__ int sh[256];
    int i = blockIdx.x * 256 + threadIdx.x;
    int v = (i < N) ? deg[i] : 0;
    sh[threadIdx.x] = v;
    __syncthreads();
    for (int off = 1; off < 256; off <<= 1) {
        int t = (threadIdx.x >= off) ? sh[threadIdx.x - off] : 0;
        __syncthreads();
        sh[threadIdx.x] += t;
        __syncthreads();
    }
    if (i < N) exsc[i] = sh[threadIdx.x] - v;
    if (threadIdx.x == 255) partials[blockIdx.x] = sh[255];
}

__global__ __launch_bounds__(512) void scan2_kernel(int* partials, int nb) {
    __shared__ int sh[512];
    int v = (threadIdx.x < nb) ? partials[threadIdx.x] : 0;
    sh[threadIdx.x] = v;
    __syncthreads();
    for (int off = 1; off < 512; off <<= 1) {
        int t = (threadIdx.x >= off) ? sh[threadIdx.x - off] : 0;
        __syncthreads();
        sh[threadIdx.x] += t;
        __syncthreads();
    }
    if (threadIdx.x < nb) partials[threadIdx.x] = sh[threadIdx.x] - v;  // exclusive
}

__global__ __launch_bounds__(256) void scan3_kernel(int* exsc, const int* __restrict__ partials,
                                                    int* cursor, int N) {
    int i = blockIdx.x * 256 + threadIdx.x;
    if (i < N) {
        int r = exsc[i] + partials[blockIdx.x];
        exsc[i] = r;
        cursor[i] = r;
    }
}

// ================= CSR fill: csr_src[slot(dst)] = src =================
__global__ __launch_bounds__(256) void fill_kernel(const int* __restrict__ src,
                                                   const int* __restrict__ dst,
                                                   int* cursor, int* csr_src, int E) {
    int e = blockIdx.x * 256 + threadIdx.x;
    if (e < E) {
        int pos = atomicAdd(&cursor[dst[e]], 1);
        csr_src[pos] = src[e];
    }
}

// ================= gather-aggregate: out[n] = sum_{e in(n)} h[src(e)] (*no[src]) =================
template <int D4, int TPN, bool SCALE>
__global__ __launch_bounds__(256) void aggregate_kernel(const float4* __restrict__ h,
                                                        const int* __restrict__ row_start,
                                                        const int* __restrict__ deg,
                                                        const int* __restrict__ csr_src,
                                                        const float* __restrict__ no,
                                                        float4* __restrict__ out, int N) {
    int tid = blockIdx.x * 256 + threadIdx.x;
    int node = tid / TPN;
    int lane = tid % TPN;
    if (node >= N) return;
    const bool active = lane < D4;
    float4 acc = make_float4(0.f, 0.f, 0.f, 0.f);
    const int start = row_start[node];
    const int d = deg[node];
    int j = 0;
    for (; j + 1 < d; j += 2) {
        int s0 = csr_src[start + j];
        int s1 = csr_src[start + j + 1];
        if (active) {
            float4 v0 = h[(size_t)s0 * D4 + lane];
            float4 v1 = h[(size_t)s1 * D4 + lane];
            float c0 = SCALE ? no[s0] : 1.0f;
            float c1 = SCALE ? no[s1] : 1.0f;
            acc.x += v0.x * c0 + v1.x * c1;
            acc.y += v0.y * c0 + v1.y * c1;
            acc.z += v0.z * c0 + v1.z * c1;
            acc.w += v0.w * c0 + v1.w * c1;
        }
    }
    if (j < d) {
        int s0 = csr_src[start + j];
        if (active) {
            float4 v0 = h[(size_t)s0 * D4 + lane];
            float c0 = SCALE ? no[s0] : 1.0f;
            acc.x += v0.x * c0;
            acc.y += v0.y * c0;
            acc.z += v0.z * c0;
            acc.w += v0.w * c0;
        }
    }
    if (active) out[(size_t)node * D4 + lane] = acc;
}

// ====== layer-3 fused aggregate (y is N x 48 dense): out[n,c<47] = relu(agg*nin + b3) ======
template <int D4, int TPN>
__global__ __launch_bounds__(256) void aggregate_final_kernel(const float4* __restrict__ y,
                                                              const int* __restrict__ row_start,
                                                              const int* __restrict__ deg,
                                                              const int* __restrict__ csr_src,
                                                              const float* __restrict__ nin,
                                                              const float* __restrict__ b3,
                                                              float* __restrict__ out, int N) {
    int tid = blockIdx.x * 256 + threadIdx.x;
    int node = tid / TPN;
    int lane = tid % TPN;
    if (node >= N) return;
    const bool active = lane < D4;
    float4 acc = make_float4(0.f, 0.f, 0.f, 0.f);
    const int start = row_start[node];
    const int d = deg[node];
    int j = 0;
    for (; j + 1 < d; j += 2) {
        int s0 = csr_src[start + j];
        int s1 = csr_src[start + j + 1];
        if (active) {
            float4 v0 = y[(size_t)s0 * D4 + lane];
            float4 v1 = y[(size_t)s1 * D4 + lane];
            acc.x += v0.x + v1.x;
            acc.y += v0.y + v1.y;
            acc.z += v0.z + v1.z;
            acc.w += v0.w + v1.w;
        }
    }
    if (j < d) {
        int s0 = csr_src[start + j];
        if (active) {
            float4 v0 = y[(size_t)s0 * D4 + lane];
            acc.x += v0.x;
            acc.y += v0.y;
            acc.z += v0.z;
            acc.w += v0.w;
        }
    }
    if (active) {
        float s = nin[node];
        float vals[4] = {acc.x, acc.y, acc.z, acc.w};
        int c0 = lane * 4;
#pragma unroll
        for (int k = 0; k < 4; ++k) {
            int c = c0 + k;
            if (c < 47) out[(size_t)node * 47 + c] = fmaxf(vals[k] * s + b3[c], 0.0f);
        }
    }
}

// ================= GEMM: out = epi ? relu(A@W *nin + b)*nout : A@W =================
// EMPIRICAL (rounds 1/3/4): specially-shaped layer-3 instantiations scratch-spilled.
// ONLY the <100,128,16> and <128,128,16> instantiations may exist; layer 3 reuses
// <128,128,16> with runtime epi=0/ostride=48 (W3 cols zero-padded via wcols=47).
// Round 7: M2=4 rows/thread x 8 cols (TJ=16, NJ4=2): 16 fmaf per ds_read_b128
// (was 8), acc stays 32 floats (power-of-2, proven-healthy register shape).
template <int K, int NOUTP, int TJ>
__global__ __launch_bounds__(256, 4) void gemm_kernel(const float* __restrict__ A,
                                                      const float* __restrict__ W, const int wcols,
                                                      const float* __restrict__ bias,
                                                      const float* __restrict__ nin,
                                                      const float* __restrict__ nout,
                                                      float* __restrict__ out, const int N,
                                                      const int epi, const int ostride) {
    constexpr int BK = 64;
    constexpr int ROWS = 256 / TJ;      // 16
    constexpr int M2 = 4;
    constexpr int BM = ROWS * M2;       // 64
    constexpr int NJ4 = NOUTP / (TJ * 4);  // 2
    constexpr int K4 = K / 4;
    constexpr int NCH = (K + BK - 1) / BK;

    __shared__ __align__(16) float Wl[BK * NOUTP];

    const int tid = threadIdx.x;
    const int tj = tid % TJ;
    const int r = tid / TJ;
    const int n0 = blockIdx.x * BM + r * M2;

    // clamped row pointers: invalid rows read row N-1 (garbage acc, never stored)
    const float4* pA[M2];
#pragma unroll
    for (int m = 0; m < M2; ++m) {
        int rm = n0 + m;
        rm = (rm < N) ? rm : (N - 1);
        pA[m] = (const float4*)A + (size_t)rm * K4;
    }

    float acc[M2][NJ4 * 4];
#pragma unroll
    for (int m = 0; m < M2; ++m)
#pragma unroll
        for (int j = 0; j < NJ4 * 4; ++j) acc[m][j] = 0.0f;

    // 1-deep register prefetch of A
    float4 an[M2];
#pragma unroll
    for (int m = 0; m < M2; ++m) an[m] = pA[m][0];

    for (int ch = 0; ch < NCH; ++ch) {
        const int k0 = ch * BK;
        const int L = (K - k0 < BK) ? (K - k0) : BK;
        if (wcols == NOUTP) {
            const float4* W4 = (const float4*)(W + (size_t)k0 * NOUTP);
            float4* Wl4 = (float4*)Wl;
            for (int i = tid; i < L * NOUTP / 4; i += 256) Wl4[i] = W4[i];
        } else {
            for (int i = tid; i < L * NOUTP; i += 256) {
                int k = i / NOUTP;
                int c = i - k * NOUTP;
                Wl[i] = (c < wcols) ? W[(size_t)(k0 + k) * wcols + c] : 0.0f;
            }
        }
        __syncthreads();

        const int L4 = L / 4;
        for (int k4 = 0; k4 < L4; ++k4) {
            float af[M2][4];
#pragma unroll
            for (int m = 0; m < M2; ++m) {
                af[m][0] = an[m].x; af[m][1] = an[m].y;
                af[m][2] = an[m].z; af[m][3] = an[m].w;
            }
            const int nk = k0 / 4 + k4 + 1;     // next global k4 (crosses chunk boundary)
            if (nk < K4) {
#pragma unroll
                for (int m = 0; m < M2; ++m) an[m] = pA[m][nk];
            }
#pragma unroll
            for (int kk = 0; kk < 4; ++kk) {
#pragma unroll
                for (int jj = 0; jj < NJ4; ++jj) {
                    const float4 w = *(const float4*)&Wl[(k4 * 4 + kk) * NOUTP + (jj * TJ + tj) * 4];
#pragma unroll
                    for (int m = 0; m < M2; ++m) {
                        acc[m][jj * 4 + 0] = fmaf(af[m][kk], w.x, acc[m][jj * 4 + 0]);
                        acc[m][jj * 4 + 1] = fmaf(af[m][kk], w.y, acc[m][jj * 4 + 1]);
                        acc[m][jj * 4 + 2] = fmaf(af[m][kk], w.z, acc[m][jj * 4 + 2]);
                        acc[m][jj * 4 + 3] = fmaf(af[m][kk], w.w, acc[m][jj * 4 + 3]);
                    }
                }
            }
        }
        __syncthreads();
    }

#pragma unroll
    for (int m = 0; m < M2; ++m) {
        const int n = n0 + m;
        if (n < N) {
            const float s_in = epi ? nin[n] : 1.0f;
            const float s_out = epi ? nout[n] : 1.0f;
#pragma unroll
            for (int jj = 0; jj < NJ4; ++jj) {
                const int c0 = (jj * TJ + tj) * 4;
                if (c0 < ostride) {
                    float v0e = acc[m][jj * 4 + 0] * s_in;
                    float v1e = acc[m][jj * 4 + 1] * s_in;
                    float v2e = acc[m][jj * 4 + 2] * s_in;
                    float v3e = acc[m][jj * 4 + 3] * s_in;
                    if (epi) {
                        v0e = fmaxf(v0e + bias[c0 + 0], 0.0f) * s_out;
                        v1e = fmaxf(v1e + bias[c0 + 1], 0.0f) * s_out;
                        v2e = fmaxf(v2e + bias[c0 + 2], 0.0f) * s_out;
                        v3e = fmaxf(v3e + bias[c0 + 3], 0.0f) * s_out;
                    }
                    float4 o = make_float4(v0e, v1e, v2e, v3e);
                    *(float4*)&out[(size_t)n * ostride + c0] = o;
                }
            }
        }
    }
}

extern "C" void kernel_launch(void* const* d_in, const int* in_sizes, int n_in,
                              void* d_out, int out_size, void* d_ws, size_t ws_size,
                              hipStream_t stream) {
    const float* x  = (const float*)d_in[0];
    const int*   ei = (const int*)d_in[1];
    const float* W1 = (const float*)d_in[2];
    const float* b1 = (const float*)d_in[3];
    const float* W2 = (const float*)d_in[4];
    const float* b2 = (const float*)d_in[5];
    const float* W3 = (const float*)d_in[6];
    const float* b3 = (const float*)d_in[7];
    float* out = (float*)d_out;

    const int N = NN;
    const int E = in_sizes[1] / 2;
    const int* src = ei;
    const int* dst = ei + E;

    // ---- workspace layout ----
    float* ws = (float*)d_ws;
    float* norm_out = ws;                       // N f
    float* norm_in  = ws + N;                   // N f
    float* bufA = ws + 2 * (size_t)N;           // N x 128 f (agg; aliased as bufY N x 48)
    float* bufB = bufA + (size_t)N * 128;       // N x 128 f (h)
    int* ip = (int*)(bufB + (size_t)N * 128);
    int* degO      = ip;                        // N i
    int* degI      = ip + N;                    // N i
    int* row_start = ip + 2 * (size_t)N;        // N i
    int* cursor    = ip + 3 * (size_t)N;        // N i
    int* csr_src   = ip + 4 * (size_t)N;        // E i
    int* partials  = csr_src + E;               // 512 i
    float* bufY = bufA;                         // N x 48 dense (layer-3 y)

    const int NB = (N + 255) / 256;             // 391 scan blocks

    // ---- degrees, norms, CSR ----
    hipMemsetAsync(degO, 0, 2 * (size_t)N * sizeof(int), stream);
    count_kernel<<<(E + 255) / 256, 256, 0, stream>>>(src, dst, degO, degI, E);
    norm_kernel<<<NB, 256, 0, stream>>>(degO, degI, norm_out, norm_in, N);
    scan1_kernel<<<NB, 256, 0, stream>>>(degI, row_start, partials, N);
    scan2_kernel<<<1, 512, 0, stream>>>(partials, NB);
    scan3_kernel<<<NB, 256, 0, stream>>>(row_start, partials, cursor, N);
    fill_kernel<<<(E + 255) / 256, 256, 0, stream>>>(src, dst, cursor, csr_src, E);

    // ---- layer 1: agg1 = gather-agg(x * no, 100); h1' = relu(agg1@W1 *nin + b1) * no ----
    aggregate_kernel<25, 32, true><<<(N * 32 + 255) / 256, 256, 0, stream>>>(
        (const float4*)x, row_start, degI, csr_src, norm_out, (float4*)bufA, N);
    gemm_kernel<100, 128, 16><<<(N + 63) / 64, 256, 0, stream>>>(
        bufA, W1, 128, b1, norm_in, norm_out, bufB, N, 1, 128);

    // ---- layer 2: agg2 = gather-agg(h1', 128); h2' = relu(agg2@W2 *nin + b2) * no ----
    aggregate_kernel<32, 32, false><<<(N * 32 + 255) / 256, 256, 0, stream>>>(
        (const float4*)bufB, row_start, degI, csr_src, nullptr, (float4*)bufA, N);
    gemm_kernel<128, 128, 16><<<(N + 63) / 64, 256, 0, stream>>>(
        bufA, W2, 128, b2, norm_in, norm_out, bufB, N, 1, 128);

    // ---- layer 3 (reordered): y = h2'@W3 — SAME instantiation as layer 2, W3 cols
    //      zero-padded 47->128, compact output stride 48; then fused final aggregate ----
    gemm_kernel<128, 128, 16><<<(N + 63) / 64, 256, 0, stream>>>(
        bufB, W3, 47, nullptr, nullptr, nullptr, bufY, N, 0, 48);
    aggregate_final_kernel<12, 16><<<(N * 16 + 255) / 256, 256, 0, stream>>>(
        (const float4*)bufY, row_start, degI, csr_src, norm_in, b3, out, N);
}